// Round 1
// baseline (1127.938 us; speedup 1.0000x reference)
//
#include <hip/hip_runtime.h>

#define DI __device__ __forceinline__

typedef __attribute__((ext_vector_type(8))) short short8;
typedef __attribute__((ext_vector_type(4))) float f32x4;

constexpr int THREADS = 512;           // 8 waves
constexpr int ROWS    = 32;            // batch rows per block
constexpr int NBLK    = 8192 / ROWS;   // 256 blocks = 256 CUs
constexpr int PITCH   = 272;           // byte pitch for K=128 bf16 rows (136 el, 16B-aligned, bank-staggered)
constexpr int PITCH2  = 528;           // byte pitch for K=256 bf16 rows

// ---- LDS layout (bytes) ----
constexpr int O_W     = 0;        // 104448 = 384*272 weight region (also fc1 256*272 + fc2 64*528)
constexpr int O_FC2   = 69632;    // fc2 weights inside W region
constexpr int O_X     = 104448;   // 17408: x double buffer (2*32*272); reused as a1 (32*528)
constexpr int O_H     = 121856;   // 8704: hidden state bf16 (32*272)
constexpr int O_A2    = 130560;   // 4608: a2 (32*144)
constexpr int O_CWT   = 135168;   // 10240: conv weights bf16, 128 rows * 80B (K=18 pad 32)
constexpr int O_PATCH = 145408;   // 2560: im2col patch (32*80)
constexpr int O_BIHE  = 147968;   // 1536 each: f32 bias tables
constexpr int O_BHHE  = 149504;
constexpr int O_BIHD  = 151040;
constexpr int O_BHHD  = 152576;
constexpr int O_FC1B  = 154112;   // 1024
constexpr int O_FC2B  = 155136;   // 256
constexpr int O_FC3B  = 155392;   // 32
constexpr int O_CB    = 155424;   // 512 conv bias
constexpr int O_FC3W  = 155936;   // 1536 fc3 weights f32
constexpr int LDS_TOTAL = 157472; // <= 163840

DI unsigned short f2bf(float f){
  union { float f; unsigned u; } v; v.f = f;
  unsigned r = (v.u + 0x7fffu + ((v.u >> 16) & 1u)) >> 16;
  return (unsigned short)r;
}
DI float bf2f(unsigned short u){
  union { unsigned u; float f; } v; v.u = ((unsigned)u) << 16;
  return v.f;
}
DI float sigm(float x){ return 1.f / (1.f + __expf(-x)); }
DI float tanh_(float x){ float e = __expf(2.f * x); return (e - 1.f) / (e + 1.f); }

// stage an (nrows x 128) f32 matrix from global into LDS as bf16, row pitch 272B
DI void load_w_k128(char* dst, const float* __restrict__ src, int nrows, int tid){
  const int total = nrows * 32;  // float4 count
  for (int i = tid; i < total; i += THREADS){
    float4 v = ((const float4*)src)[i];
    int e = i << 2;
    int n = e >> 7, k = e & 127;
    unsigned lo = (unsigned)f2bf(v.x) | ((unsigned)f2bf(v.y) << 16);
    unsigned hi = (unsigned)f2bf(v.z) | ((unsigned)f2bf(v.w) << 16);
    *(uint2*)(dst + n * PITCH + k * 2) = make_uint2(lo, hi);
  }
}
// stage an (nrows x 256) f32 matrix, row pitch 528B
DI void load_w_k256(char* dst, const float* __restrict__ src, int nrows, int tid){
  const int total = nrows * 64;
  for (int i = tid; i < total; i += THREADS){
    float4 v = ((const float4*)src)[i];
    int e = i << 2;
    int n = e >> 8, k = e & 255;
    unsigned lo = (unsigned)f2bf(v.x) | ((unsigned)f2bf(v.y) << 16);
    unsigned hi = (unsigned)f2bf(v.z) | ((unsigned)f2bf(v.w) << 16);
    *(uint2*)(dst + n * PITCH2 + k * 2) = make_uint2(lo, hi);
  }
}

// (32 x 128) @ (128 x 384): per-wave gate-aligned n-tiles {g*128 + wq*32 + p*16}
DI void gemm_g3(f32x4 (&acc)[3][2], const char* A, const char* W,
                int mt, int wq, int l15, int quad){
  #pragma unroll
  for (int kt = 0; kt < 4; ++kt){
    short8 a = *(const short8*)(A + (mt*16 + l15)*PITCH + kt*64 + quad*16);
    #pragma unroll
    for (int g = 0; g < 3; ++g){
      #pragma unroll
      for (int p = 0; p < 2; ++p){
        int nt = g*8 + wq*2 + p;
        short8 b = *(const short8*)(W + (nt*16 + l15)*PITCH + kt*64 + quad*16);
        acc[g][p] = __builtin_amdgcn_mfma_f32_16x16x32_bf16(a, b, acc[g][p], 0, 0, 0);
      }
    }
  }
}

// GRU gate math + h update (h stored bf16 in LDS). gi/gh hold gate-aligned cols.
DI void gru_update(const f32x4 (&gi)[3][2], const f32x4 (&gh)[3][2], char* hb,
                   const float* bih, const float* bhh,
                   int mt, int wq, int l15, int quad){
  #pragma unroll
  for (int p = 0; p < 2; ++p){
    int jj = wq*32 + p*16 + l15;
    float bir = bih[jj],      bhr = bhh[jj];
    float biz = bih[128+jj],  bhz = bhh[128+jj];
    float bin = bih[256+jj],  bhn = bhh[256+jj];
    #pragma unroll
    for (int r = 0; r < 4; ++r){
      int m = mt*16 + quad*4 + r;
      unsigned short* hp = (unsigned short*)(hb + m*PITCH + jj*2);
      float hold = bf2f(*hp);
      float rg = sigm(gi[0][p][r] + bir + gh[0][p][r] + bhr);
      float zg = sigm(gi[1][p][r] + biz + gh[1][p][r] + bhz);
      float ng = tanh_(gi[2][p][r] + bin + rg*(gh[2][p][r] + bhn));
      *hp = f2bf((1.f - zg)*ng + zg*hold);
    }
  }
}

__global__ void __launch_bounds__(THREADS, 2)
gru_fused(const float* __restrict__ past,
          const float* __restrict__ conv_w, const float* __restrict__ conv_b,
          const float* __restrict__ bn_gamma, const float* __restrict__ bn_beta,
          const float* __restrict__ bn_mean, const float* __restrict__ bn_var,
          const float* __restrict__ enc_wih, const float* __restrict__ enc_whh,
          const float* __restrict__ enc_bih, const float* __restrict__ enc_bhh,
          const float* __restrict__ dec_wih, const float* __restrict__ dec_whh,
          const float* __restrict__ dec_bih, const float* __restrict__ dec_bhh,
          const float* __restrict__ fc1_w, const float* __restrict__ fc1_b,
          const float* __restrict__ fc2_w, const float* __restrict__ fc2_b,
          const float* __restrict__ fc3_w, const float* __restrict__ fc3_b,
          float* __restrict__ out)
{
  extern __shared__ char smem[];
  const int tid  = threadIdx.x;
  const int lane = tid & 63, wave = tid >> 6;
  const int mt = wave >> 2, wq = wave & 3;       // m-tile (0..1), gate-quarter (0..3)
  const int l15 = lane & 15, quad = lane >> 4;
  const int b0 = blockIdx.x * ROWS;

  // ---- init: zero h / patch / conv-weight pads ----
  for (int i = tid; i < 8704/4;  i += THREADS) ((unsigned*)(smem + O_H))[i] = 0u;
  for (int i = tid; i < 2560/4;  i += THREADS) ((unsigned*)(smem + O_PATCH))[i] = 0u;
  for (int i = tid; i < 10240/4; i += THREADS) ((unsigned*)(smem + O_CWT))[i] = 0u;
  __syncthreads();
  for (int i = tid; i < 384; i += THREADS){
    ((float*)(smem + O_BIHE))[i] = enc_bih[i];
    ((float*)(smem + O_BHHE))[i] = enc_bhh[i];
    ((float*)(smem + O_BIHD))[i] = dec_bih[i];
    ((float*)(smem + O_BHHD))[i] = dec_bhh[i];
    ((float*)(smem + O_FC3W))[i] = fc3_w[i];
  }
  for (int i = tid; i < 256; i += THREADS) ((float*)(smem + O_FC1B))[i] = fc1_b[i];
  for (int i = tid; i < 64;  i += THREADS) ((float*)(smem + O_FC2B))[i] = fc2_b[i];
  for (int i = tid; i < 6;   i += THREADS) ((float*)(smem + O_FC3B))[i] = fc3_b[i];
  for (int i = tid; i < 128; i += THREADS) ((float*)(smem + O_CB))[i]   = conv_b[i];
  for (int i = tid; i < 2304; i += THREADS){  // conv_w (oc, c, kk) -> cwT[oc][k=c*3+kk]
    int oc = i / 18, kk = i - oc*18;
    *(unsigned short*)(smem + O_CWT + oc*80 + kk*2) = f2bf(conv_w[i]);
  }
  const float s_bn = bn_gamma[0] * rsqrtf(bn_var[0] + 1e-5f);
  const float o_bn = bn_beta[0] - bn_mean[0] * s_bn;

  // ================= encoder: 32 chunks of 4 steps =================
  f32x4 gi[4][3][2];
  for (int chunk = 0; chunk < 32; ++chunk){
    // --- phase A: w_ih resident; conv + x-path GEMM for 4 steps ---
    load_w_k128(smem + O_W, enc_wih, 384, tid);
    __syncthreads();
    #pragma unroll
    for (int tc = 0; tc < 4; ++tc){
      const int t = chunk*4 + tc;
      for (int e = tid; e < 576; e += THREADS){       // im2col patch (32 x 18)
        int m = e / 18, r18 = e - m*18;
        int c = r18 / 3, kk = r18 - c*3;
        int tin = t - 1 + kk;
        float v = (tin >= 0 && tin < 128) ? past[(size_t)(b0+m)*768 + c*128 + tin] : 0.f;
        *(unsigned short*)(smem + O_PATCH + m*80 + r18*2) = f2bf(v);
      }
      __syncthreads();
      char* xb = smem + O_X + (tc & 1) * 8704;
      {
        short8 ap = *(const short8*)(smem + O_PATCH + (mt*16 + l15)*80 + quad*16);
        #pragma unroll
        for (int p = 0; p < 2; ++p){
          int nt = wq*2 + p;
          short8 bp = *(const short8*)(smem + O_CWT + (nt*16 + l15)*80 + quad*16);
          f32x4 cacc = {0.f, 0.f, 0.f, 0.f};
          cacc = __builtin_amdgcn_mfma_f32_16x16x32_bf16(ap, bp, cacc, 0, 0, 0);
          int n = nt*16 + l15;
          float cb = ((const float*)(smem + O_CB))[n];
          #pragma unroll
          for (int r = 0; r < 4; ++r){
            int m = mt*16 + quad*4 + r;
            float v = fmaxf(cacc[r] + cb, 0.f);       // bias + relu
            v = s_bn * v + o_bn;                      // batchnorm
            *(unsigned short*)(xb + m*PITCH + n*2) = f2bf(v);
          }
        }
      }
      __syncthreads();
      #pragma unroll
      for (int g = 0; g < 3; ++g)
        #pragma unroll
        for (int p = 0; p < 2; ++p) gi[tc][g][p] = (f32x4){0.f,0.f,0.f,0.f};
      gemm_g3(gi[tc], xb, smem + O_W, mt, wq, l15, quad);
    }
    __syncthreads();
    // --- phase B: w_hh resident; recurrent GEMM + gate math for 4 steps ---
    load_w_k128(smem + O_W, enc_whh, 384, tid);
    __syncthreads();
    #pragma unroll
    for (int tc = 0; tc < 4; ++tc){
      f32x4 gh[3][2];
      #pragma unroll
      for (int g = 0; g < 3; ++g)
        #pragma unroll
        for (int p = 0; p < 2; ++p) gh[g][p] = (f32x4){0.f,0.f,0.f,0.f};
      gemm_g3(gh, smem + O_H, smem + O_W, mt, wq, l15, quad);
      __syncthreads();                                 // all h reads done
      gru_update(gi[tc], gh, smem + O_H,
                 (const float*)(smem + O_BIHE), (const float*)(smem + O_BHHE),
                 mt, wq, l15, quad);
      __syncthreads();                                 // h writes visible
    }
  }

  // ================= decoder init =================
  // gi0 = state_past @ dec_wih^T  (dec input step 0 = encoder final h; steps 1..29 inputs are zero)
  load_w_k128(smem + O_W, dec_wih, 384, tid);
  __syncthreads();
  f32x4 gi0[3][2];
  #pragma unroll
  for (int g = 0; g < 3; ++g)
    #pragma unroll
    for (int p = 0; p < 2; ++p) gi0[g][p] = (f32x4){0.f,0.f,0.f,0.f};
  gemm_g3(gi0, smem + O_H, smem + O_W, mt, wq, l15, quad);
  __syncthreads();
  for (int i = tid; i < 8704/4; i += THREADS) ((unsigned*)(smem + O_H))[i] = 0u;  // decoder h0 = 0
  const int prow = tid / 6, pcol = tid - prow*6;
  float present = 0.f;
  if (tid < 192) present = past[(size_t)(b0+prow)*768 + pcol*128 + 127];          // past[:,:, -1]
  __syncthreads();

  // ================= decoder: 30 steps =================
  for (int s = 0; s < 30; ++s){
    load_w_k128(smem + O_W, dec_whh, 384, tid);
    __syncthreads();
    f32x4 gh[3][2];
    #pragma unroll
    for (int g = 0; g < 3; ++g)
      #pragma unroll
      for (int p = 0; p < 2; ++p) gh[g][p] = (f32x4){0.f,0.f,0.f,0.f};
    gemm_g3(gh, smem + O_H, smem + O_W, mt, wq, l15, quad);
    __syncthreads();
    f32x4 gx[3][2];
    #pragma unroll
    for (int g = 0; g < 3; ++g)
      #pragma unroll
      for (int p = 0; p < 2; ++p)
        #pragma unroll
        for (int r = 0; r < 4; ++r)
          gx[g][p][r] = (s == 0) ? gi0[g][p][r] : 0.f;
    gru_update(gx, gh, smem + O_H,
               (const float*)(smem + O_BIHD), (const float*)(smem + O_BHHD),
               mt, wq, l15, quad);
    __syncthreads();
    // --- MLP ---
    load_w_k128(smem + O_W, fc1_w, 256, tid);
    load_w_k256(smem + O_FC2, fc2_w, 64, tid);
    __syncthreads();
    // fc1: (32x128)@(128x256), relu
    f32x4 a1[4];
    #pragma unroll
    for (int j = 0; j < 4; ++j) a1[j] = (f32x4){0.f,0.f,0.f,0.f};
    #pragma unroll
    for (int kt = 0; kt < 4; ++kt){
      short8 a = *(const short8*)(smem + O_H + (mt*16 + l15)*PITCH + kt*64 + quad*16);
      #pragma unroll
      for (int j = 0; j < 4; ++j){
        int nt = wq*4 + j;
        short8 b = *(const short8*)(smem + O_W + (nt*16 + l15)*PITCH + kt*64 + quad*16);
        a1[j] = __builtin_amdgcn_mfma_f32_16x16x32_bf16(a, b, a1[j], 0, 0, 0);
      }
    }
    #pragma unroll
    for (int j = 0; j < 4; ++j){
      int n = (wq*4 + j)*16 + l15;
      float bb = ((const float*)(smem + O_FC1B))[n];
      #pragma unroll
      for (int r = 0; r < 4; ++r){
        int m = mt*16 + quad*4 + r;
        *(unsigned short*)(smem + O_X + m*PITCH2 + n*2) = f2bf(fmaxf(a1[j][r] + bb, 0.f));
      }
    }
    __syncthreads();
    // fc2: (32x256)@(256x64)
    {
      const int mtl = wave & 1, nt2 = wave >> 1;
      f32x4 a2 = {0.f,0.f,0.f,0.f};
      #pragma unroll
      for (int kt = 0; kt < 8; ++kt){
        short8 a = *(const short8*)(smem + O_X + (mtl*16 + l15)*PITCH2 + kt*64 + quad*16);
        short8 b = *(const short8*)(smem + O_FC2 + (nt2*16 + l15)*PITCH2 + kt*64 + quad*16);
        a2 = __builtin_amdgcn_mfma_f32_16x16x32_bf16(a, b, a2, 0, 0, 0);
      }
      int n = nt2*16 + l15;
      float bb = ((const float*)(smem + O_FC2B))[n];
      #pragma unroll
      for (int r = 0; r < 4; ++r){
        int m = mtl*16 + quad*4 + r;
        *(unsigned short*)(smem + O_A2 + m*144 + n*2) = f2bf(a2[r] + bb);
      }
    }
    __syncthreads();
    // fc3 (6x64) on VALU + present accumulate + store
    if (tid < 192){
      float acc = ((const float*)(smem + O_FC3B))[pcol];
      const float* w3 = (const float*)(smem + O_FC3W) + pcol*64;
      #pragma unroll
      for (int kc = 0; kc < 8; ++kc){
        short8 av = *(const short8*)(smem + O_A2 + prow*144 + kc*16);
        f32x4 wa = *(const f32x4*)(w3 + kc*8);
        f32x4 wb = *(const f32x4*)(w3 + kc*8 + 4);
        #pragma unroll
        for (int j = 0; j < 4; ++j) acc += bf2f((unsigned short)av[j])   * wa[j];
        #pragma unroll
        for (int j = 0; j < 4; ++j) acc += bf2f((unsigned short)av[j+4]) * wb[j];
      }
      present += acc;
      out[(size_t)(b0+prow)*180 + pcol*30 + s] = present;   // (B, 6, 30)
    }
    __syncthreads();
  }
}

extern "C" void kernel_launch(void* const* d_in, const int* in_sizes, int n_in,
                              void* d_out, int out_size, void* d_ws, size_t ws_size,
                              hipStream_t stream) {
  (void)in_sizes; (void)n_in; (void)out_size; (void)d_ws; (void)ws_size;
  const float* past     = (const float*)d_in[0];
  const float* conv_w   = (const float*)d_in[1];
  const float* conv_b   = (const float*)d_in[2];
  const float* bn_gamma = (const float*)d_in[3];
  const float* bn_beta  = (const float*)d_in[4];
  const float* bn_mean  = (const float*)d_in[5];
  const float* bn_var   = (const float*)d_in[6];
  const float* enc_wih  = (const float*)d_in[7];
  const float* enc_whh  = (const float*)d_in[8];
  const float* enc_bih  = (const float*)d_in[9];
  const float* enc_bhh  = (const float*)d_in[10];
  const float* dec_wih  = (const float*)d_in[11];
  const float* dec_whh  = (const float*)d_in[12];
  const float* dec_bih  = (const float*)d_in[13];
  const float* dec_bhh  = (const float*)d_in[14];
  const float* fc1_w    = (const float*)d_in[15];
  const float* fc1_b    = (const float*)d_in[16];
  const float* fc2_w    = (const float*)d_in[17];
  const float* fc2_b    = (const float*)d_in[18];
  const float* fc3_w    = (const float*)d_in[19];
  const float* fc3_b    = (const float*)d_in[20];

  static bool attr_set = [](){
    hipFuncSetAttribute((const void*)gru_fused,
                        hipFuncAttributeMaxDynamicSharedMemorySize, LDS_TOTAL);
    return true;
  }();
  (void)attr_set;
  // idempotent; also call unconditionally in case of multi-device contexts
  hipFuncSetAttribute((const void*)gru_fused,
                      hipFuncAttributeMaxDynamicSharedMemorySize, LDS_TOTAL);

  gru_fused<<<NBLK, THREADS, LDS_TOTAL, stream>>>(
      past, conv_w, conv_b, bn_gamma, bn_beta, bn_mean, bn_var,
      enc_wih, enc_whh, enc_bih, enc_bhh,
      dec_wih, dec_whh, dec_bih, dec_bhh,
      fc1_w, fc1_b, fc2_w, fc2_b, fc3_w, fc3_b,
      (float*)d_out);
}

// Round 2
// 623.168 us; speedup vs baseline: 1.8100x; 1.8100x over previous
//
#include <hip/hip_runtime.h>

#define DI __device__ __forceinline__

typedef __attribute__((ext_vector_type(8))) short short8;
typedef __attribute__((ext_vector_type(4))) float f32x4;

constexpr int THREADS = 512;           // 8 waves
constexpr int ROWS    = 32;            // batch rows per block
constexpr int NBLK    = 8192 / ROWS;   // 256 blocks = 256 CUs
constexpr int PITCH   = 272;           // byte pitch, K=128 bf16 rows (2-way-bank-safe)
constexpr int PITCH2  = 528;           // byte pitch, K=256 bf16 rows

// ---- LDS layout (bytes) ----
// O_W multi-use: [enc] staging for wih/whh/cwT then past_l (50688);
//                [dec] fc1 (69632) + fc2 (33792) + a1 (16896) = 120320
constexpr int O_W     = 0;
constexpr int O_FC2   = 69632;
constexpr int O_A1    = 103424;
constexpr int O_PATCH = 120320;   // 2 x 2560 patch double buffer (32 rows x 80B)
constexpr int O_X     = 125440;   // 8704 x tile (a2 32x144 in decoder)
constexpr int O_H     = 134144;   // 8704 hidden state bf16
constexpr int O_FC3W  = 142848;   // 1536 fc3 weights f32
constexpr int LDS_TOTAL = 144384;

DI unsigned short f2bf(float f){
  union { float f; unsigned u; } v; v.f = f;
  return (unsigned short)((v.u + 0x7fffu + ((v.u >> 16) & 1u)) >> 16);
}
DI float bf2f(unsigned short u){
  union { unsigned u; float f; } v; v.u = ((unsigned)u) << 16;
  return v.f;
}
DI float sigm(float x){ return 1.f / (1.f + __expf(-x)); }
DI float tanh_(float x){
  float ax = fabsf(x);
  float e = __expf(-2.f * ax);
  float t = (1.f - e) / (1.f + e);
  return copysignf(t, x);
}
DI f32x4 mfma16(short8 a, short8 b, f32x4 c){
  return __builtin_amdgcn_mfma_f32_16x16x32_bf16(a, b, c, 0, 0, 0);
}

// one-time: stage (nrows x 128) f32 -> bf16 LDS, pitch 272
DI void load_w_k128(char* dst, const float* __restrict__ src, int nrows, int tid){
  const int total = nrows * 32;
  for (int i = tid; i < total; i += THREADS){
    float4 v = ((const float4*)src)[i];
    int e = i << 2;
    int n = e >> 7, k = e & 127;
    unsigned lo = (unsigned)f2bf(v.x) | ((unsigned)f2bf(v.y) << 16);
    unsigned hi = (unsigned)f2bf(v.z) | ((unsigned)f2bf(v.w) << 16);
    *(uint2*)(dst + n * PITCH + k * 2) = make_uint2(lo, hi);
  }
}
// one-time: stage (nrows x 256) f32 -> bf16 LDS, pitch 528
DI void load_w_k256(char* dst, const float* __restrict__ src, int nrows, int tid){
  const int total = nrows * 64;
  for (int i = tid; i < total; i += THREADS){
    float4 v = ((const float4*)src)[i];
    int e = i << 2;
    int n = e >> 8, k = e & 255;
    unsigned lo = (unsigned)f2bf(v.x) | ((unsigned)f2bf(v.y) << 16);
    unsigned hi = (unsigned)f2bf(v.z) | ((unsigned)f2bf(v.w) << 16);
    *(uint2*)(dst + n * PITCH2 + k * 2) = make_uint2(lo, hi);
  }
}

__global__ void __launch_bounds__(THREADS, 2)
gru_fused(const float* __restrict__ past,
          const float* __restrict__ conv_w, const float* __restrict__ conv_b,
          const float* __restrict__ bn_gamma, const float* __restrict__ bn_beta,
          const float* __restrict__ bn_mean, const float* __restrict__ bn_var,
          const float* __restrict__ enc_wih, const float* __restrict__ enc_whh,
          const float* __restrict__ enc_bih, const float* __restrict__ enc_bhh,
          const float* __restrict__ dec_wih, const float* __restrict__ dec_whh,
          const float* __restrict__ dec_bih, const float* __restrict__ dec_bhh,
          const float* __restrict__ fc1_w, const float* __restrict__ fc1_b,
          const float* __restrict__ fc2_w, const float* __restrict__ fc2_b,
          const float* __restrict__ fc3_w, const float* __restrict__ fc3_b,
          float* __restrict__ out)
{
  extern __shared__ char smem[];
  const int tid  = threadIdx.x;
  const int lane = tid & 63, w = tid >> 6;        // wave 0..7 owns gate-col slice w*16..
  const int l15  = lane & 15, quad = lane >> 4;
  const int b0   = blockIdx.x * ROWS;
  const int col  = w * 16 + l15;                  // this thread's gate/h column

  // ---- per-thread bias registers (one-time global scalar reads) ----
  const float br_e  = enc_bih[col]       + enc_bhh[col];
  const float bz_e  = enc_bih[128 + col] + enc_bhh[128 + col];
  const float bin_e = enc_bih[256 + col];
  const float bhn_e = enc_bhh[256 + col];
  const float br_d  = dec_bih[col]       + dec_bhh[col];
  const float bz_d  = dec_bih[128 + col] + dec_bhh[128 + col];
  const float bin_d = dec_bih[256 + col];
  const float bhn_d = dec_bhh[256 + col];
  const float cb_t  = conv_b[col];
  const float s_bn  = bn_gamma[0] * rsqrtf(bn_var[0] + 1e-5f);
  const float o_bn  = bn_beta[0] - bn_mean[0] * s_bn;
  const float fb1a  = fc1_b[w * 32 + l15];
  const float fb1b  = fc1_b[w * 32 + 16 + l15];
  const int   mt2   = w & 1, nt2 = w >> 1;        // fc2 decomposition
  const float fb2   = fc2_b[nt2 * 16 + l15];

  // ---- stage encoder weights once, pull fragments to registers ----
  short8 wf[3][4];   // input-weight frags (enc_wih now, dec_wih later): [gate][kt]
  short8 wh[3][4];   // recurrent-weight frags
  load_w_k128(smem + O_W, enc_wih, 384, tid);
  __syncthreads();
  #pragma unroll
  for (int g = 0; g < 3; ++g)
    #pragma unroll
    for (int kt = 0; kt < 4; ++kt)
      wf[g][kt] = *(const short8*)(smem + O_W + (g*128 + col)*PITCH + kt*64 + quad*16);
  __syncthreads();
  load_w_k128(smem + O_W, enc_whh, 384, tid);
  __syncthreads();
  #pragma unroll
  for (int g = 0; g < 3; ++g)
    #pragma unroll
    for (int kt = 0; kt < 4; ++kt)
      wh[g][kt] = *(const short8*)(smem + O_W + (g*128 + col)*PITCH + kt*64 + quad*16);
  __syncthreads();

  // ---- conv weights: cwT[h][k=c*3+kk] bf16, 80B rows, K padded to 32 ----
  for (int i = tid; i < 2560; i += THREADS) ((unsigned*)(smem + O_W))[i] = 0u;
  __syncthreads();
  for (int i = tid; i < 2304; i += THREADS){
    int oc = i / 18, kk = i - oc * 18;
    *(unsigned short*)(smem + O_W + oc*80 + kk*2) = f2bf(conv_w[i]);
  }
  __syncthreads();
  const short8 cwf = *(const short8*)(smem + O_W + col*80 + quad*16);
  __syncthreads();

  // ---- past -> LDS bf16, layout past_l[m][c][tpos 0..131], zero padded ----
  for (int i = tid; i < 12672; i += THREADS) ((unsigned*)(smem + O_W))[i] = 0u;
  for (int i = tid; i < 1280;  i += THREADS) ((unsigned*)(smem + O_PATCH))[i] = 0u;
  for (int i = tid; i < 2176;  i += THREADS) ((unsigned*)(smem + O_H))[i] = 0u;
  __syncthreads();
  for (int i4 = tid; i4 < 6144; i4 += THREADS){
    int m = i4 / 192, rem = i4 - m*192, c = rem >> 5, t4 = (rem & 31) << 2;
    float4 v = *(const float4*)(past + (size_t)(b0 + m)*768 + c*128 + t4);
    unsigned short* dst = (unsigned short*)(smem + O_W + ((m*6 + c)*132 + t4 + 1)*2);
    dst[0] = f2bf(v.x); dst[1] = f2bf(v.y); dst[2] = f2bf(v.z); dst[3] = f2bf(v.w);
  }
  for (int i = tid; i < 384; i += THREADS) ((float*)(smem + O_FC3W))[i] = fc3_w[i];

  // patch-build constants (thread -> up to 2 of 576 elements)
  const int e0 = tid;                 // always < 576
  const int m0 = e0 / 18, r0 = e0 - m0*18, c0 = r0 / 3, k0 = r0 - c0*3;
  const int e1 = tid + 512;           // valid for tid < 64
  const int m1 = e1 / 18, r1 = e1 - m1*18, c1 = r1 / 3, k1 = r1 - c1*3;
  auto build_patch = [&](int t){      // patch[m][k18] = past[b][c][t-1+kk] (tpos = t+kk)
    char* pb = smem + O_PATCH + (t & 1)*2560;
    *(unsigned short*)(pb + m0*80 + r0*2) =
        *(const unsigned short*)(smem + O_W + ((m0*6 + c0)*132 + t + k0)*2);
    if (e1 < 576)
      *(unsigned short*)(pb + m1*80 + r1*2) =
          *(const unsigned short*)(smem + O_W + ((m1*6 + c1)*132 + t + k1)*2);
  };
  __syncthreads();
  build_patch(0);
  __syncthreads();

  // ---- accumulators / state ----
  f32x4 acc[2][3], accn[2];
  #pragma unroll
  for (int mt = 0; mt < 2; ++mt){
    #pragma unroll
    for (int g = 0; g < 3; ++g) acc[mt][g] = (f32x4){0.f,0.f,0.f,0.f};
    accn[mt] = (f32x4){0.f,0.f,0.f,0.f};
  }
  float hreg[8];
  #pragma unroll
  for (int i = 0; i < 8; ++i) hreg[i] = 0.f;

  // ================= encoder: 128 steps, 2 barriers each =================
  for (int t = 0; t < 128; ++t){
    // ---- phase A: conv x[t] (MFMA) + bn -> x LDS; build patch[t+1]; write h(t)
    {
      const char* pb = smem + O_PATCH + (t & 1)*2560;
      short8 pa0 = *(const short8*)(pb + l15*80 + quad*16);
      short8 pa1 = *(const short8*)(pb + (16 + l15)*80 + quad*16);
      f32x4 c0a = (f32x4){0.f,0.f,0.f,0.f}, c1a = (f32x4){0.f,0.f,0.f,0.f};
      c0a = mfma16(pa0, cwf, c0a);
      c1a = mfma16(pa1, cwf, c1a);
      #pragma unroll
      for (int r = 0; r < 4; ++r){
        int mr = quad*4 + r;
        float vx0 = s_bn * fmaxf(c0a[r] + cb_t, 0.f) + o_bn;
        float vx1 = s_bn * fmaxf(c1a[r] + cb_t, 0.f) + o_bn;
        *(unsigned short*)(smem + O_X + mr*PITCH + col*2)        = f2bf(vx0);
        *(unsigned short*)(smem + O_X + (16 + mr)*PITCH + col*2) = f2bf(vx1);
      }
    }
    if (t < 127) build_patch(t + 1);
    if (t > 0){
      #pragma unroll
      for (int mt = 0; mt < 2; ++mt)
        #pragma unroll
        for (int r = 0; r < 4; ++r)
          *(unsigned short*)(smem + O_H + (mt*16 + quad*4 + r)*PITCH + col*2) =
              f2bf(hreg[mt*4 + r]);
    }
    __syncthreads();   // B1: x[t], h(t), patch[t+1] visible

    // ---- phase B: gi + gh GEMMs (weights in registers), gate math
    short8 xa[2][4], ha[2][4];
    #pragma unroll
    for (int mt = 0; mt < 2; ++mt)
      #pragma unroll
      for (int kt = 0; kt < 4; ++kt){
        xa[mt][kt] = *(const short8*)(smem + O_X + (mt*16 + l15)*PITCH + kt*64 + quad*16);
        ha[mt][kt] = *(const short8*)(smem + O_H + (mt*16 + l15)*PITCH + kt*64 + quad*16);
      }
    #pragma unroll
    for (int mt = 0; mt < 2; ++mt)
      #pragma unroll
      for (int kt = 0; kt < 4; ++kt){
        acc[mt][0] = mfma16(xa[mt][kt], wf[0][kt], acc[mt][0]);
        acc[mt][1] = mfma16(xa[mt][kt], wf[1][kt], acc[mt][1]);
        acc[mt][2] = mfma16(xa[mt][kt], wf[2][kt], acc[mt][2]);
        acc[mt][0] = mfma16(ha[mt][kt], wh[0][kt], acc[mt][0]);   // r: gi+gh folded
        acc[mt][1] = mfma16(ha[mt][kt], wh[1][kt], acc[mt][1]);   // z: gi+gh folded
        accn[mt]   = mfma16(ha[mt][kt], wh[2][kt], accn[mt]);     // n: gh separate
      }
    #pragma unroll
    for (int mt = 0; mt < 2; ++mt)
      #pragma unroll
      for (int r = 0; r < 4; ++r){
        float rg = sigm(acc[mt][0][r] + br_e);
        float zg = sigm(acc[mt][1][r] + bz_e);
        float ng = tanh_(acc[mt][2][r] + bin_e + rg*(accn[mt][r] + bhn_e));
        hreg[mt*4 + r] = ng + zg*(hreg[mt*4 + r] - ng);
      }
    #pragma unroll
    for (int mt = 0; mt < 2; ++mt){
      #pragma unroll
      for (int g = 0; g < 3; ++g) acc[mt][g] = (f32x4){0.f,0.f,0.f,0.f};
      accn[mt] = (f32x4){0.f,0.f,0.f,0.f};
    }
    __syncthreads();   // B2: all x/h reads done
  }

  // ================= decoder init =================
  // write h_enc, compute gi0 = h_enc @ dec_wih^T
  #pragma unroll
  for (int mt = 0; mt < 2; ++mt)
    #pragma unroll
    for (int r = 0; r < 4; ++r)
      *(unsigned short*)(smem + O_H + (mt*16 + quad*4 + r)*PITCH + col*2) =
          f2bf(hreg[mt*4 + r]);
  __syncthreads();
  load_w_k128(smem + O_W, dec_wih, 384, tid);
  __syncthreads();
  #pragma unroll
  for (int g = 0; g < 3; ++g)
    #pragma unroll
    for (int kt = 0; kt < 4; ++kt)
      wf[g][kt] = *(const short8*)(smem + O_W + (g*128 + col)*PITCH + kt*64 + quad*16);
  {
    short8 hea[2][4];
    #pragma unroll
    for (int mt = 0; mt < 2; ++mt)
      #pragma unroll
      for (int kt = 0; kt < 4; ++kt)
        hea[mt][kt] = *(const short8*)(smem + O_H + (mt*16 + l15)*PITCH + kt*64 + quad*16);
    #pragma unroll
    for (int mt = 0; mt < 2; ++mt)
      #pragma unroll
      for (int kt = 0; kt < 4; ++kt){
        acc[mt][0] = mfma16(hea[mt][kt], wf[0][kt], acc[mt][0]);
        acc[mt][1] = mfma16(hea[mt][kt], wf[1][kt], acc[mt][1]);
        acc[mt][2] = mfma16(hea[mt][kt], wf[2][kt], acc[mt][2]);
      }
  }
  __syncthreads();   // h_enc reads + wf frag reads done
  for (int i = tid; i < 2176; i += THREADS) ((unsigned*)(smem + O_H))[i] = 0u;
  #pragma unroll
  for (int i = 0; i < 8; ++i) hreg[i] = 0.f;
  load_w_k128(smem + O_W, dec_whh, 384, tid);
  __syncthreads();
  #pragma unroll
  for (int g = 0; g < 3; ++g)
    #pragma unroll
    for (int kt = 0; kt < 4; ++kt)
      wh[g][kt] = *(const short8*)(smem + O_W + (g*128 + col)*PITCH + kt*64 + quad*16);
  __syncthreads();
  load_w_k128(smem + O_W, fc1_w, 256, tid);
  load_w_k256(smem + O_FC2, fc2_w, 64, tid);
  const int prow = tid / 6, pcol = tid - prow*6;
  float present = 0.f, fb3 = 0.f;
  if (tid < 192){
    present = past[(size_t)(b0 + prow)*768 + pcol*128 + 127];
    fb3 = fc3_b[pcol];
  }
  __syncthreads();

  // ================= decoder: 30 steps =================
  for (int s = 0; s < 30; ++s){
    // gh GEMM (acc holds gi0 at s=0, else 0)
    {
      short8 ha[2][4];
      #pragma unroll
      for (int mt = 0; mt < 2; ++mt)
        #pragma unroll
        for (int kt = 0; kt < 4; ++kt)
          ha[mt][kt] = *(const short8*)(smem + O_H + (mt*16 + l15)*PITCH + kt*64 + quad*16);
      #pragma unroll
      for (int mt = 0; mt < 2; ++mt)
        #pragma unroll
        for (int kt = 0; kt < 4; ++kt){
          acc[mt][0] = mfma16(ha[mt][kt], wh[0][kt], acc[mt][0]);
          acc[mt][1] = mfma16(ha[mt][kt], wh[1][kt], acc[mt][1]);
          accn[mt]   = mfma16(ha[mt][kt], wh[2][kt], accn[mt]);
        }
    }
    #pragma unroll
    for (int mt = 0; mt < 2; ++mt)
      #pragma unroll
      for (int r = 0; r < 4; ++r){
        float rg = sigm(acc[mt][0][r] + br_d);
        float zg = sigm(acc[mt][1][r] + bz_d);
        float ng = tanh_(acc[mt][2][r] + bin_d + rg*(accn[mt][r] + bhn_d));
        hreg[mt*4 + r] = ng + zg*(hreg[mt*4 + r] - ng);
      }
    #pragma unroll
    for (int mt = 0; mt < 2; ++mt){
      #pragma unroll
      for (int g = 0; g < 3; ++g) acc[mt][g] = (f32x4){0.f,0.f,0.f,0.f};
      accn[mt] = (f32x4){0.f,0.f,0.f,0.f};
    }
    __syncthreads();   // D1: h reads done
    #pragma unroll
    for (int mt = 0; mt < 2; ++mt)
      #pragma unroll
      for (int r = 0; r < 4; ++r)
        *(unsigned short*)(smem + O_H + (mt*16 + quad*4 + r)*PITCH + col*2) =
            f2bf(hreg[mt*4 + r]);
    __syncthreads();   // D2: h(s+1) visible

    // fc1: (32x128)@(128x256) + relu -> a1
    {
      short8 hf2[2][4];
      #pragma unroll
      for (int mt = 0; mt < 2; ++mt)
        #pragma unroll
        for (int kt = 0; kt < 4; ++kt)
          hf2[mt][kt] = *(const short8*)(smem + O_H + (mt*16 + l15)*PITCH + kt*64 + quad*16);
      f32x4 a1a[2][2];
      #pragma unroll
      for (int mt = 0; mt < 2; ++mt)
        #pragma unroll
        for (int j = 0; j < 2; ++j) a1a[mt][j] = (f32x4){0.f,0.f,0.f,0.f};
      #pragma unroll
      for (int j = 0; j < 2; ++j)
        #pragma unroll
        for (int kt = 0; kt < 4; ++kt){
          short8 b = *(const short8*)(smem + O_W + ((w*2 + j)*16 + l15)*PITCH + kt*64 + quad*16);
          a1a[0][j] = mfma16(hf2[0][kt], b, a1a[0][j]);
          a1a[1][j] = mfma16(hf2[1][kt], b, a1a[1][j]);
        }
      #pragma unroll
      for (int mt = 0; mt < 2; ++mt)
        #pragma unroll
        for (int j = 0; j < 2; ++j){
          float bb = j ? fb1b : fb1a;
          #pragma unroll
          for (int r = 0; r < 4; ++r)
            *(unsigned short*)(smem + O_A1 + (mt*16 + quad*4 + r)*PITCH2 +
                               (w*32 + j*16 + l15)*2) = f2bf(fmaxf(a1a[mt][j][r] + bb, 0.f));
        }
    }
    __syncthreads();   // D3: a1 visible

    // fc2: (32x256)@(256x64) -> a2
    {
      f32x4 a2a = (f32x4){0.f,0.f,0.f,0.f};
      #pragma unroll
      for (int kt = 0; kt < 8; ++kt){
        short8 a = *(const short8*)(smem + O_A1 + (mt2*16 + l15)*PITCH2 + kt*64 + quad*16);
        short8 b = *(const short8*)(smem + O_FC2 + (nt2*16 + l15)*PITCH2 + kt*64 + quad*16);
        a2a = mfma16(a, b, a2a);
      }
      #pragma unroll
      for (int r = 0; r < 4; ++r)
        *(unsigned short*)(smem + O_X + (mt2*16 + quad*4 + r)*144 + (nt2*16 + l15)*2) =
            f2bf(a2a[r] + fb2);
    }
    __syncthreads();   // D4: a2 visible

    // fc3 (6x64, VALU) + present accumulate + store
    if (tid < 192){
      float o = fb3;
      const float* w3 = (const float*)(smem + O_FC3W) + pcol*64;
      #pragma unroll
      for (int kc = 0; kc < 8; ++kc){
        short8 av = *(const short8*)(smem + O_X + prow*144 + kc*16);
        #pragma unroll
        for (int j = 0; j < 8; ++j)
          o += bf2f((unsigned short)av[j]) * w3[kc*8 + j];
      }
      present += o;
      out[(size_t)(b0 + prow)*180 + pcol*30 + s] = present;   // (B, 6, 30)
    }
    // no trailing barrier needed: next conflicting LDS write is after D1/D2 of s+1
  }
}

extern "C" void kernel_launch(void* const* d_in, const int* in_sizes, int n_in,
                              void* d_out, int out_size, void* d_ws, size_t ws_size,
                              hipStream_t stream) {
  (void)in_sizes; (void)n_in; (void)out_size; (void)d_ws; (void)ws_size;
  const float* past     = (const float*)d_in[0];
  const float* conv_w   = (const float*)d_in[1];
  const float* conv_b   = (const float*)d_in[2];
  const float* bn_gamma = (const float*)d_in[3];
  const float* bn_beta  = (const float*)d_in[4];
  const float* bn_mean  = (const float*)d_in[5];
  const float* bn_var   = (const float*)d_in[6];
  const float* enc_wih  = (const float*)d_in[7];
  const float* enc_whh  = (const float*)d_in[8];
  const float* enc_bih  = (const float*)d_in[9];
  const float* enc_bhh  = (const float*)d_in[10];
  const float* dec_wih  = (const float*)d_in[11];
  const float* dec_whh  = (const float*)d_in[12];
  const float* dec_bih  = (const float*)d_in[13];
  const float* dec_bhh  = (const float*)d_in[14];
  const float* fc1_w    = (const float*)d_in[15];
  const float* fc1_b    = (const float*)d_in[16];
  const float* fc2_w    = (const float*)d_in[17];
  const float* fc2_b    = (const float*)d_in[18];
  const float* fc3_w    = (const float*)d_in[19];
  const float* fc3_b    = (const float*)d_in[20];

  hipFuncSetAttribute((const void*)gru_fused,
                      hipFuncAttributeMaxDynamicSharedMemorySize, LDS_TOTAL);

  gru_fused<<<NBLK, THREADS, LDS_TOTAL, stream>>>(
      past, conv_w, conv_b, bn_gamma, bn_beta, bn_mean, bn_var,
      enc_wih, enc_whh, enc_bih, enc_bhh,
      dec_wih, dec_whh, dec_bih, dec_bhh,
      fc1_w, fc1_b, fc2_w, fc2_b, fc3_w, fc3_b,
      (float*)d_out);
}

// Round 3
// 600.161 us; speedup vs baseline: 1.8794x; 1.0383x over previous
//
#include <hip/hip_runtime.h>

#define DI __device__ __forceinline__

typedef __attribute__((ext_vector_type(8))) short short8;
typedef __attribute__((ext_vector_type(4))) float f32x4;

constexpr int THREADS = 512;           // 8 waves
constexpr int ROWS    = 32;            // batch rows per block
constexpr int NBLK    = 8192 / ROWS;   // 256 blocks = 256 CUs
constexpr int PITCH   = 272;           // K=128 bf16 rows; 272%128==16 -> b128 reads conflict-free
constexpr int PITCH2  = 528;           // K=256 bf16 rows; 528%128==16 -> conflict-free
constexpr int SPITCH  = 256;           // one-time staging pitch (conflicts don't matter there)

// ---- LDS layout (bytes) ----
constexpr int O_STAGE = 0;        // 98304 = 384*256: staging; then past_l (50688) in encoder
constexpr int O_PATCH = 98304;    // 10240: patch_all 128 rows x 80B (4 steps x 32 rows)
constexpr int O_XALL  = 108544;   // 34816: x_all 128 rows x 272B (4 steps x 32 rows)
constexpr int O_H     = 143360;   // 2 x 8704 hidden-state double buffer
constexpr int HBUF    = 8704;
constexpr int O_FC3W  = 160768;   // 1536: fc3 weights f32
constexpr int LDS_TOTAL = 162304; // <= 163840
// decoder aliases (stage/patch/x_all dead during decoder steps)
constexpr int O_A1D   = 98304;    // 16896: a1 (32 x 528)
constexpr int O_A2D   = 115200;   // 4608:  a2 (32 x 144)

DI unsigned short f2bf(float f){
  union { float f; unsigned u; } v; v.f = f;
  return (unsigned short)((v.u + 0x7fffu + ((v.u >> 16) & 1u)) >> 16);
}
DI float bf2f(unsigned short u){
  union { unsigned u; float f; } v; v.u = ((unsigned)u) << 16;
  return v.f;
}
DI float u2f_lo(unsigned u){ union { unsigned u; float f; } v; v.u = u << 16;        return v.f; }
DI float u2f_hi(unsigned u){ union { unsigned u; float f; } v; v.u = u & 0xffff0000u; return v.f; }
DI float sigm(float x){ return 1.f / (1.f + __expf(-x)); }
DI float tanh_(float x){
  float ax = fabsf(x);
  float e = __expf(-2.f * ax);
  float t = (1.f - e) / (1.f + e);
  return copysignf(t, x);
}
DI f32x4 mfma16(short8 a, short8 b, f32x4 c){
  return __builtin_amdgcn_mfma_f32_16x16x32_bf16(a, b, c, 0, 0, 0);
}
DI uint2 pack4(f32x4 v){
  return make_uint2((unsigned)f2bf(v[0]) | ((unsigned)f2bf(v[1]) << 16),
                    (unsigned)f2bf(v[2]) | ((unsigned)f2bf(v[3]) << 16));
}
DI f32x4 unpack4(uint2 u){
  return (f32x4){u2f_lo(u.x), u2f_hi(u.x), u2f_lo(u.y), u2f_hi(u.y)};
}

// one-time: stage (nrows x 128) f32 -> bf16 LDS, pitch SPITCH
DI void stage_k128(char* dst, const float* __restrict__ src, int nrows, int tid){
  const int total = nrows * 32;
  for (int i = tid; i < total; i += THREADS){
    float4 v = ((const float4*)src)[i];
    int e = i << 2;
    int n = e >> 7, k = e & 127;
    unsigned lo = (unsigned)f2bf(v.x) | ((unsigned)f2bf(v.y) << 16);
    unsigned hi = (unsigned)f2bf(v.z) | ((unsigned)f2bf(v.w) << 16);
    *(uint2*)(dst + n * SPITCH + k * 2) = make_uint2(lo, hi);
  }
}
// one-time: stage (nrows x 256) f32 -> bf16 LDS, pitch 528
DI void stage_k256(char* dst, const float* __restrict__ src, int nrows, int tid){
  const int total = nrows * 64;
  for (int i = tid; i < total; i += THREADS){
    float4 v = ((const float4*)src)[i];
    int e = i << 2;
    int n = e >> 8, k = e & 255;
    unsigned lo = (unsigned)f2bf(v.x) | ((unsigned)f2bf(v.y) << 16);
    unsigned hi = (unsigned)f2bf(v.z) | ((unsigned)f2bf(v.w) << 16);
    *(uint2*)(dst + n * PITCH2 + k * 2) = make_uint2(lo, hi);
  }
}

__global__ void __launch_bounds__(THREADS, 2)
gru_fused(const float* __restrict__ past,
          const float* __restrict__ conv_w, const float* __restrict__ conv_b,
          const float* __restrict__ bn_gamma, const float* __restrict__ bn_beta,
          const float* __restrict__ bn_mean, const float* __restrict__ bn_var,
          const float* __restrict__ enc_wih, const float* __restrict__ enc_whh,
          const float* __restrict__ enc_bih, const float* __restrict__ enc_bhh,
          const float* __restrict__ dec_wih, const float* __restrict__ dec_whh,
          const float* __restrict__ dec_bih, const float* __restrict__ dec_bhh,
          const float* __restrict__ fc1_w, const float* __restrict__ fc1_b,
          const float* __restrict__ fc2_w, const float* __restrict__ fc2_b,
          const float* __restrict__ fc3_w, const float* __restrict__ fc3_b,
          float* __restrict__ out)
{
  extern __shared__ char smem[];
  const int tid  = threadIdx.x;
  const int lane = tid & 63, w = tid >> 6;        // wave w owns gate-col slice w*16..w*16+15
  const int l15  = lane & 15, quad = lane >> 4;
  const int b0   = blockIdx.x * ROWS;
  const int col  = w * 16 + l15;

  // ---- per-thread bias registers ----
  const float br_e  = enc_bih[col]       + enc_bhh[col];
  const float bz_e  = enc_bih[128 + col] + enc_bhh[128 + col];
  const float bin_e = enc_bih[256 + col];
  const float bhn_e = enc_bhh[256 + col];
  const float br_d  = dec_bih[col]       + dec_bhh[col];
  const float bz_d  = dec_bih[128 + col] + dec_bhh[128 + col];
  const float bin_d = dec_bih[256 + col];
  const float bhn_d = dec_bhh[256 + col];
  const float cb_t  = conv_b[col];
  const float s_bn  = bn_gamma[0] * rsqrtf(bn_var[0] + 1e-5f);
  const float o_bn  = bn_beta[0] - bn_mean[0] * s_bn;
  const float fb1a  = fc1_b[w * 32 + l15];
  const float fb1b  = fc1_b[w * 32 + 16 + l15];
  const int   mt2   = w & 1, nt2 = w >> 1;        // fc2 decomposition
  const float fb2   = fc2_b[nt2 * 16 + l15];

  // ---- zero h double buffer ----
  for (int i = tid; i < 2*HBUF/4; i += THREADS) ((unsigned*)(smem + O_H))[i] = 0u;

  // ---- stage encoder weights once, pull B-fragments to registers ----
  short8 wf[3][4], wh[3][4];
  stage_k128(smem + O_STAGE, enc_wih, 384, tid);
  __syncthreads();
  #pragma unroll
  for (int g = 0; g < 3; ++g)
    #pragma unroll
    for (int kt = 0; kt < 4; ++kt)
      wf[g][kt] = *(const short8*)(smem + O_STAGE + (g*128 + col)*SPITCH + kt*64 + quad*16);
  __syncthreads();
  stage_k128(smem + O_STAGE, enc_whh, 384, tid);
  __syncthreads();
  #pragma unroll
  for (int g = 0; g < 3; ++g)
    #pragma unroll
    for (int kt = 0; kt < 4; ++kt)
      wh[g][kt] = *(const short8*)(smem + O_STAGE + (g*128 + col)*SPITCH + kt*64 + quad*16);
  __syncthreads();

  // ---- conv weights: cwT[oc][k=c*3+kk] bf16, 80B rows, K padded 18->32 ----
  for (int i = tid; i < 2560; i += THREADS) ((unsigned*)(smem + O_STAGE))[i] = 0u;
  __syncthreads();
  for (int i = tid; i < 2304; i += THREADS){
    int oc = i / 18, kk = i - oc * 18;
    *(unsigned short*)(smem + O_STAGE + oc*80 + kk*2) = f2bf(conv_w[i]);
  }
  __syncthreads();
  const short8 cwf = *(const short8*)(smem + O_STAGE + col*80 + quad*16);
  __syncthreads();

  // ---- past -> LDS bf16: past_l[m][c][tpos 0..131] (shift +1, zero padded) ----
  for (int i = tid; i < 12672; i += THREADS) ((unsigned*)(smem + O_STAGE))[i] = 0u;
  __syncthreads();
  for (int i4 = tid; i4 < 6144; i4 += THREADS){
    int m = i4 / 192, rem = i4 - m*192, c = rem >> 5, t4 = (rem & 31) << 2;
    float4 v = *(const float4*)(past + (size_t)(b0 + m)*768 + c*128 + t4);
    unsigned short* dst = (unsigned short*)(smem + O_STAGE + ((m*6 + c)*132 + t4 + 1)*2);
    dst[0] = f2bf(v.x); dst[1] = f2bf(v.y); dst[2] = f2bf(v.z); dst[3] = f2bf(v.w);
  }
  for (int i = tid; i < 384; i += THREADS) ((float*)(smem + O_FC3W))[i] = fc3_w[i];
  __syncthreads();

  // patch-build constants: entry e -> (m, r18=(c,kk)); each thread covers e0 (+e1 if tid<64)
  const int e0 = tid;
  const int m0 = e0 / 18, r0 = e0 - m0*18, c0 = r0 / 3, k0 = r0 - c0*3;
  const int e1 = tid + 512;
  const int m1 = e1 / 18, r1 = e1 - m1*18, c1 = r1 / 3, k1 = r1 - c1*3;

  // build patch_all rows tc*32+m for steps t0..t0+3 (one entry)
  auto patch_entry = [&](int t0, int m, int r18, int c, int k){
    int base = (m*6 + c)*132 + t0 + k;            // short index into past_l
    const unsigned* pl = (const unsigned*)(smem + O_STAGE);
    unsigned w0 = pl[base >> 1], w1 = pl[(base >> 1) + 1], w2 = pl[(base >> 1) + 2];
    int sh = (base & 1) * 16;
    unsigned long long lo = (unsigned long long)w0 | ((unsigned long long)w1 << 32);
    unsigned long long hi = (unsigned long long)w1 | ((unsigned long long)w2 << 32);
    unsigned a01 = (unsigned)(lo >> sh);          // shorts t0+k, t0+k+1
    unsigned a23 = (unsigned)(hi >> sh);          // shorts t0+k+2, t0+k+3
    char* pb = smem + O_PATCH + m*80 + r18*2;
    *(unsigned short*)(pb)          = (unsigned short)(a01 & 0xffff);
    *(unsigned short*)(pb + 2560)   = (unsigned short)(a01 >> 16);
    *(unsigned short*)(pb + 5120)   = (unsigned short)(a23 & 0xffff);
    *(unsigned short*)(pb + 7680)   = (unsigned short)(a23 >> 16);
  };

  // ---- accumulator/state registers ----
  uint2 gi_pk[4][2][3];                 // packed-bf16 gi for 4 steps: [tc][mt][gate]
  float hreg[8];
  #pragma unroll
  for (int i = 0; i < 8; ++i) hreg[i] = 0.f;

  // ================= encoder: 32 chunks of (phase A + 4 light steps) =================
  for (int chunk = 0; chunk < 32; ++chunk){
    const int t0 = chunk * 4;
    // ---- phase A1: build 4 patches (reads past_l, writes patch_all) ----
    patch_entry(t0, m0, r0, c0, k0);
    if (e1 < 576) patch_entry(t0, m1, r1, c1, k1);
    __syncthreads();
    // ---- phase A2: conv as M=128 GEMM + bias/relu/bn -> x_all ----
    #pragma unroll
    for (int mt8 = 0; mt8 < 8; ++mt8){
      short8 pa = *(const short8*)(smem + O_PATCH + (mt8*16 + l15)*80 + quad*16);
      f32x4 cc = (f32x4){0.f,0.f,0.f,0.f};
      cc = mfma16(pa, cwf, cc);
      #pragma unroll
      for (int r = 0; r < 4; ++r){
        int mrow = mt8*16 + quad*4 + r;
        float vx = s_bn * fmaxf(cc[r] + cb_t, 0.f) + o_bn;
        *(unsigned short*)(smem + O_XALL + mrow*PITCH + col*2) = f2bf(vx);
      }
    }
    __syncthreads();
    // ---- phase A3: gi GEMM for 4 steps (M=128), pack to bf16 regs ----
    #pragma unroll
    for (int tc = 0; tc < 4; ++tc)
      #pragma unroll
      for (int mt = 0; mt < 2; ++mt){
        short8 a[4];
        #pragma unroll
        for (int kt = 0; kt < 4; ++kt)
          a[kt] = *(const short8*)(smem + O_XALL + ((tc*2 + mt)*16 + l15)*PITCH + kt*64 + quad*16);
        f32x4 g0 = (f32x4){0.f,0.f,0.f,0.f}, g1 = g0, g2 = g0;
        #pragma unroll
        for (int kt = 0; kt < 4; ++kt){
          g0 = mfma16(a[kt], wf[0][kt], g0);
          g1 = mfma16(a[kt], wf[1][kt], g1);
          g2 = mfma16(a[kt], wf[2][kt], g2);
        }
        gi_pk[tc][mt][0] = pack4(g0);
        gi_pk[tc][mt][1] = pack4(g1);
        gi_pk[tc][mt][2] = pack4(g2);
      }
    // x_all reads protected by next chunk's A1 barrier

    // ---- 4 recurrent steps: gh GEMM + gate math, 1 barrier each ----
    #pragma unroll
    for (int tc = 0; tc < 4; ++tc){
      const int t = t0 + tc;
      const char* hr = smem + O_H + (t & 1) * HBUF;
      char*       hw = smem + O_H + ((t + 1) & 1) * HBUF;
      f32x4 accr[2], accz[2], accn2[2], gin[2];
      #pragma unroll
      for (int mt = 0; mt < 2; ++mt){
        accr[mt]  = unpack4(gi_pk[tc][mt][0]);
        accz[mt]  = unpack4(gi_pk[tc][mt][1]);
        gin[mt]   = unpack4(gi_pk[tc][mt][2]);
        accn2[mt] = (f32x4){0.f,0.f,0.f,0.f};
      }
      short8 ha[2][4];
      #pragma unroll
      for (int mt = 0; mt < 2; ++mt)
        #pragma unroll
        for (int kt = 0; kt < 4; ++kt)
          ha[mt][kt] = *(const short8*)(hr + (mt*16 + l15)*PITCH + kt*64 + quad*16);
      #pragma unroll
      for (int mt = 0; mt < 2; ++mt)
        #pragma unroll
        for (int kt = 0; kt < 4; ++kt){
          accr[mt]  = mfma16(ha[mt][kt], wh[0][kt], accr[mt]);
          accz[mt]  = mfma16(ha[mt][kt], wh[1][kt], accz[mt]);
          accn2[mt] = mfma16(ha[mt][kt], wh[2][kt], accn2[mt]);
        }
      #pragma unroll
      for (int mt = 0; mt < 2; ++mt)
        #pragma unroll
        for (int r = 0; r < 4; ++r){
          float rg = sigm(accr[mt][r] + br_e);
          float zg = sigm(accz[mt][r] + bz_e);
          float ng = tanh_(gin[mt][r] + bin_e + rg*(accn2[mt][r] + bhn_e));
          hreg[mt*4 + r] = ng + zg*(hreg[mt*4 + r] - ng);
        }
      #pragma unroll
      for (int mt = 0; mt < 2; ++mt)
        #pragma unroll
        for (int r = 0; r < 4; ++r)
          *(unsigned short*)(hw + (mt*16 + quad*4 + r)*PITCH + col*2) = f2bf(hreg[mt*4 + r]);
      __syncthreads();   // h(t+1) visible; h(t) reads complete
    }
  }
  // after t=127: h_enc lives in hbuf[0] (and hreg)

  // ================= decoder init =================
  // dec_wih frags + gi0 = h_enc @ dec_wih^T
  stage_k128(smem + O_STAGE, dec_wih, 384, tid);
  __syncthreads();
  #pragma unroll
  for (int g = 0; g < 3; ++g)
    #pragma unroll
    for (int kt = 0; kt < 4; ++kt)
      wf[g][kt] = *(const short8*)(smem + O_STAGE + (g*128 + col)*SPITCH + kt*64 + quad*16);
  f32x4 gi0r[2], gi0z[2], gi0n[2];
  {
    short8 hea[2][4];
    #pragma unroll
    for (int mt = 0; mt < 2; ++mt)
      #pragma unroll
      for (int kt = 0; kt < 4; ++kt)
        hea[mt][kt] = *(const short8*)(smem + O_H + (mt*16 + l15)*PITCH + kt*64 + quad*16);
    #pragma unroll
    for (int mt = 0; mt < 2; ++mt){
      gi0r[mt] = (f32x4){0.f,0.f,0.f,0.f}; gi0z[mt] = gi0r[mt]; gi0n[mt] = gi0r[mt];
      #pragma unroll
      for (int kt = 0; kt < 4; ++kt){
        gi0r[mt] = mfma16(hea[mt][kt], wf[0][kt], gi0r[mt]);
        gi0z[mt] = mfma16(hea[mt][kt], wf[1][kt], gi0z[mt]);
        gi0n[mt] = mfma16(hea[mt][kt], wf[2][kt], gi0n[mt]);
      }
    }
  }
  __syncthreads();
  stage_k128(smem + O_STAGE, dec_whh, 384, tid);
  __syncthreads();
  #pragma unroll
  for (int g = 0; g < 3; ++g)
    #pragma unroll
    for (int kt = 0; kt < 4; ++kt)
      wh[g][kt] = *(const short8*)(smem + O_STAGE + (g*128 + col)*SPITCH + kt*64 + quad*16);
  __syncthreads();
  // fc1/fc2 B-frags -> registers
  short8 f1f[2][4], f2f[8];
  stage_k128(smem + O_STAGE, fc1_w, 256, tid);
  __syncthreads();
  #pragma unroll
  for (int j = 0; j < 2; ++j)
    #pragma unroll
    for (int kt = 0; kt < 4; ++kt)
      f1f[j][kt] = *(const short8*)(smem + O_STAGE + (w*32 + j*16 + l15)*SPITCH + kt*64 + quad*16);
  __syncthreads();
  stage_k256(smem + O_STAGE, fc2_w, 64, tid);
  __syncthreads();
  #pragma unroll
  for (int kt = 0; kt < 8; ++kt)
    f2f[kt] = *(const short8*)(smem + O_STAGE + (nt2*16 + l15)*PITCH2 + kt*64 + quad*16);
  __syncthreads();
  // zero decoder h0 (buffer 1), reset hreg, present init
  for (int i = tid; i < HBUF/4; i += THREADS) ((unsigned*)(smem + O_H + HBUF))[i] = 0u;
  #pragma unroll
  for (int i = 0; i < 8; ++i) hreg[i] = 0.f;
  const int prow = tid / 6, pcol = tid - prow*6;
  float present = 0.f, fb3 = 0.f;
  if (tid < 192){
    present = past[(size_t)(b0 + prow)*768 + pcol*128 + 127];
    fb3 = fc3_b[pcol];
  }
  __syncthreads();

  // ================= decoder: 30 steps, 3 barriers each =================
  for (int s = 0; s < 30; ++s){
    const char* hr = smem + O_H + (1 - (s & 1)) * HBUF;
    char*       hw = smem + O_H + (s & 1) * HBUF;
    f32x4 accr[2], accz[2], accn2[2], gin[2];
    #pragma unroll
    for (int mt = 0; mt < 2; ++mt){
      if (s == 0){ accr[mt] = gi0r[mt]; accz[mt] = gi0z[mt]; gin[mt] = gi0n[mt]; }
      else       { accr[mt] = (f32x4){0.f,0.f,0.f,0.f}; accz[mt] = accr[mt]; gin[mt] = accr[mt]; }
      accn2[mt] = (f32x4){0.f,0.f,0.f,0.f};
    }
    {
      short8 ha[2][4];
      #pragma unroll
      for (int mt = 0; mt < 2; ++mt)
        #pragma unroll
        for (int kt = 0; kt < 4; ++kt)
          ha[mt][kt] = *(const short8*)(hr + (mt*16 + l15)*PITCH + kt*64 + quad*16);
      #pragma unroll
      for (int mt = 0; mt < 2; ++mt)
        #pragma unroll
        for (int kt = 0; kt < 4; ++kt){
          accr[mt]  = mfma16(ha[mt][kt], wh[0][kt], accr[mt]);
          accz[mt]  = mfma16(ha[mt][kt], wh[1][kt], accz[mt]);
          accn2[mt] = mfma16(ha[mt][kt], wh[2][kt], accn2[mt]);
        }
    }
    #pragma unroll
    for (int mt = 0; mt < 2; ++mt)
      #pragma unroll
      for (int r = 0; r < 4; ++r){
        float rg = sigm(accr[mt][r] + br_d);
        float zg = sigm(accz[mt][r] + bz_d);
        float ng = tanh_(gin[mt][r] + bin_d + rg*(accn2[mt][r] + bhn_d));
        hreg[mt*4 + r] = ng + zg*(hreg[mt*4 + r] - ng);
      }
    #pragma unroll
    for (int mt = 0; mt < 2; ++mt)
      #pragma unroll
      for (int r = 0; r < 4; ++r)
        *(unsigned short*)(hw + (mt*16 + quad*4 + r)*PITCH + col*2) = f2bf(hreg[mt*4 + r]);
    __syncthreads();   // D1: h(s+1) visible

    // fc1: (32x128)@(128x256) + relu -> a1 (B-frags in regs)
    {
      short8 hf[2][4];
      #pragma unroll
      for (int mt = 0; mt < 2; ++mt)
        #pragma unroll
        for (int kt = 0; kt < 4; ++kt)
          hf[mt][kt] = *(const short8*)(hw + (mt*16 + l15)*PITCH + kt*64 + quad*16);
      f32x4 a1a[2][2];
      #pragma unroll
      for (int mt = 0; mt < 2; ++mt)
        #pragma unroll
        for (int j = 0; j < 2; ++j) a1a[mt][j] = (f32x4){0.f,0.f,0.f,0.f};
      #pragma unroll
      for (int j = 0; j < 2; ++j)
        #pragma unroll
        for (int kt = 0; kt < 4; ++kt){
          a1a[0][j] = mfma16(hf[0][kt], f1f[j][kt], a1a[0][j]);
          a1a[1][j] = mfma16(hf[1][kt], f1f[j][kt], a1a[1][j]);
        }
      #pragma unroll
      for (int mt = 0; mt < 2; ++mt)
        #pragma unroll
        for (int j = 0; j < 2; ++j){
          float bb = j ? fb1b : fb1a;
          #pragma unroll
          for (int r = 0; r < 4; ++r)
            *(unsigned short*)(smem + O_A1D + (mt*16 + quad*4 + r)*PITCH2 +
                               (w*32 + j*16 + l15)*2) = f2bf(fmaxf(a1a[mt][j][r] + bb, 0.f));
        }
    }
    __syncthreads();   // D2: a1 visible

    // fc2: (32x256)@(256x64) -> a2 (B-frags in regs)
    {
      f32x4 a2a = (f32x4){0.f,0.f,0.f,0.f};
      #pragma unroll
      for (int kt = 0; kt < 8; ++kt){
        short8 a = *(const short8*)(smem + O_A1D + (mt2*16 + l15)*PITCH2 + kt*64 + quad*16);
        a2a = mfma16(a, f2f[kt], a2a);
      }
      #pragma unroll
      for (int r = 0; r < 4; ++r)
        *(unsigned short*)(smem + O_A2D + (mt2*16 + quad*4 + r)*144 + (nt2*16 + l15)*2) =
            f2bf(a2a[r] + fb2);
    }
    __syncthreads();   // D3: a2 visible

    // fc3 (6x64, VALU) + present accumulate + store
    if (tid < 192){
      float o = fb3;
      const float* w3 = (const float*)(smem + O_FC3W) + pcol*64;
      #pragma unroll
      for (int kc = 0; kc < 8; ++kc){
        short8 av = *(const short8*)(smem + O_A2D + prow*144 + kc*16);
        #pragma unroll
        for (int j = 0; j < 8; ++j)
          o += bf2f((unsigned short)av[j]) * w3[kc*8 + j];
      }
      present += o;
      out[(size_t)(b0 + prow)*180 + pcol*30 + s] = present;   // (B, 6, 30)
    }
    // fc3's a2 reads are protected by next step's D1+D2 barriers
  }
}

extern "C" void kernel_launch(void* const* d_in, const int* in_sizes, int n_in,
                              void* d_out, int out_size, void* d_ws, size_t ws_size,
                              hipStream_t stream) {
  (void)in_sizes; (void)n_in; (void)out_size; (void)d_ws; (void)ws_size;
  const float* past     = (const float*)d_in[0];
  const float* conv_w   = (const float*)d_in[1];
  const float* conv_b   = (const float*)d_in[2];
  const float* bn_gamma = (const float*)d_in[3];
  const float* bn_beta  = (const float*)d_in[4];
  const float* bn_mean  = (const float*)d_in[5];
  const float* bn_var   = (const float*)d_in[6];
  const float* enc_wih  = (const float*)d_in[7];
  const float* enc_whh  = (const float*)d_in[8];
  const float* enc_bih  = (const float*)d_in[9];
  const float* enc_bhh  = (const float*)d_in[10];
  const float* dec_wih  = (const float*)d_in[11];
  const float* dec_whh  = (const float*)d_in[12];
  const float* dec_bih  = (const float*)d_in[13];
  const float* dec_bhh  = (const float*)d_in[14];
  const float* fc1_w    = (const float*)d_in[15];
  const float* fc1_b    = (const float*)d_in[16];
  const float* fc2_w    = (const float*)d_in[17];
  const float* fc2_b    = (const float*)d_in[18];
  const float* fc3_w    = (const float*)d_in[19];
  const float* fc3_b    = (const float*)d_in[20];

  hipFuncSetAttribute((const void*)gru_fused,
                      hipFuncAttributeMaxDynamicSharedMemorySize, LDS_TOTAL);

  gru_fused<<<NBLK, THREADS, LDS_TOTAL, stream>>>(
      past, conv_w, conv_b, bn_gamma, bn_beta, bn_mean, bn_var,
      enc_wih, enc_whh, enc_bih, enc_bhh,
      dec_wih, dec_whh, dec_bih, dec_bhh,
      fc1_w, fc1_b, fc2_w, fc2_b, fc3_w, fc3_b,
      (float*)d_out);
}